// Round 1
// baseline (93.062 us; speedup 1.0000x reference)
//
#include <hip/hip_runtime.h>
#include <math.h>

namespace {
constexpr int B_ = 4096;
constexpr int C_ = 12288;
constexpr float DEG2RAD = 0.017453292519943295f;
constexpr float TWO_R = 2.0f * 6371.0f;     // 2 * EARTH_RADIUS
constexpr float INV_TAU = 1.0f / 75.0f;
}

// Precompute per-centroid trig: sin(lat/2), cos(lat/2), sin(lon/2), cos(lon/2), cos(lat)
__global__ void centroid_trig_kernel(const float* __restrict__ centroids,
                                     float* __restrict__ ct) {
    int c = blockIdx.x * blockDim.x + threadIdx.x;
    if (c >= C_) return;
    float lat = centroids[2 * c] * DEG2RAD;
    float lon = centroids[2 * c + 1] * DEG2RAD;
    ct[c]          = sinf(0.5f * lat);
    ct[C_ + c]     = cosf(0.5f * lat);
    ct[2 * C_ + c] = sinf(0.5f * lon);
    ct[3 * C_ + c] = cosf(0.5f * lon);
    ct[4 * C_ + c] = cosf(lat);
}

__device__ __forceinline__ float wave_red_add(float v) {
#pragma unroll
    for (int off = 32; off > 0; off >>= 1) v += __shfl_down(v, off, 64);
    return v;
}

// One block per row b. Single pass over the logits row; three running sums:
//   W = sum_c w_c,  T = sum_c w_c * l_c,  S = sum_c exp(l_c)
// loss_b = log(S) - T/W   (EPS dropped: contributes <= ~1e-3, threshold 0.1975)
__global__ __launch_bounds__(256) void row_loss_kernel(
    const float* __restrict__ logits, const float* __restrict__ latlon,
    const float* __restrict__ ct, float* __restrict__ row_loss) {
    const int b = blockIdx.x;
    const float lat1 = latlon[2 * b] * DEG2RAD;
    const float lon1 = latlon[2 * b + 1] * DEG2RAD;
    const float slh1 = sinf(0.5f * lat1), clh1 = cosf(0.5f * lat1);
    const float snh1 = sinf(0.5f * lon1), cnh1 = cosf(0.5f * lon1);
    const float cl1 = cosf(lat1);
    const float* __restrict__ slh2 = ct;
    const float* __restrict__ clh2 = ct + C_;
    const float* __restrict__ snh2 = ct + 2 * C_;
    const float* __restrict__ cnh2 = ct + 3 * C_;
    const float* __restrict__ cl2  = ct + 4 * C_;
    const float* __restrict__ lrow = logits + (size_t)b * C_;

    float W = 0.f, T = 0.f, S = 0.f;
    for (int c = threadIdx.x; c < C_; c += 256) {
        float l = lrow[c];
        // sin((lat2-lat1)/2) via half-angle difference identity (no cancellation)
        float sd = slh2[c] * clh1 - clh2[c] * slh1;
        float td = snh2[c] * cnh1 - cnh2[c] * snh1;
        float a = sd * sd + (cl1 * cl2[c]) * (td * td);
        a = fminf(fmaxf(a, 0.0f), 1.0f);
        float d = TWO_R * asinf(sqrtf(a));
        float w = __expf(-d * INV_TAU);
        W += w;
        T = fmaf(w, l, T);
        S += __expf(l);
    }
    W = wave_red_add(W);
    T = wave_red_add(T);
    S = wave_red_add(S);
    __shared__ float red[3][4];
    const int lane = threadIdx.x & 63, wv = threadIdx.x >> 6;
    if (lane == 0) { red[0][wv] = W; red[1][wv] = T; red[2][wv] = S; }
    __syncthreads();
    if (threadIdx.x == 0) {
        float Wt = red[0][0] + red[0][1] + red[0][2] + red[0][3];
        float Tt = red[1][0] + red[1][1] + red[1][2] + red[1][3];
        float St = red[2][0] + red[2][1] + red[2][2] + red[2][3];
        Wt = fmaxf(Wt, 1e-30f);
        row_loss[b] = logf(St) - Tt / Wt;
    }
}

__global__ __launch_bounds__(256) void final_reduce_kernel(
    const float* __restrict__ row_loss, float* __restrict__ out) {
    float s = 0.f;
    for (int i = threadIdx.x; i < B_; i += 256) s += row_loss[i];
    s = wave_red_add(s);
    __shared__ float red[4];
    const int lane = threadIdx.x & 63, wv = threadIdx.x >> 6;
    if (lane == 0) red[wv] = s;
    __syncthreads();
    if (threadIdx.x == 0)
        out[0] = (red[0] + red[1] + red[2] + red[3]) * (1.0f / B_);
}

extern "C" void kernel_launch(void* const* d_in, const int* in_sizes, int n_in,
                              void* d_out, int out_size, void* d_ws, size_t ws_size,
                              hipStream_t stream) {
    const float* pred_logits = (const float*)d_in[0];  // [B, C] f32
    const float* latlon      = (const float*)d_in[1];  // [B, 2] f32
    const float* centroids   = (const float*)d_in[2];  // [C, 2] f32
    // d_in[3] geocell_indices is unused by the reference.
    float* ct       = (float*)d_ws;      // 5*C floats of centroid trig
    float* row_loss = ct + 5 * C_;       // B floats
    float* out      = (float*)d_out;

    centroid_trig_kernel<<<(C_ + 255) / 256, 256, 0, stream>>>(centroids, ct);
    row_loss_kernel<<<B_, 256, 0, stream>>>(pred_logits, latlon, ct, row_loss);
    final_reduce_kernel<<<1, 256, 0, stream>>>(row_loss, out);
}

// Round 2
// 59.246 us; speedup vs baseline: 1.5708x; 1.5708x over previous
//
#include <hip/hip_runtime.h>
#include <math.h>

namespace {
constexpr int B_ = 4096;
constexpr int C_ = 12288;
constexpr float DEG2RAD = 0.017453292519943295f;
constexpr float KN = -169.8933333333f;   // -(2*EARTH_RADIUS)/TAU ; w = exp(KN * asin(s))
constexpr float PI_2F = 1.57079632679f;
// Abramowitz & Stegun 4.4.46: asin(x) = pi/2 - sqrt(1-x)*poly(x), x in [0,1], |err|<=2e-8
constexpr float A0 = 1.5707963050f;
constexpr float A1 = -0.2145988016f;
constexpr float A2 = 0.0889789874f;
constexpr float A3 = -0.0501743046f;
constexpr float A4 = 0.0308918810f;
constexpr float A5 = -0.0170881256f;
constexpr float A6 = 0.0066700901f;
constexpr float A7 = -0.0012624911f;
}

// Precompute per-centroid HALF unit-sphere coords: 0.5*(x,y,z).
// Then ||hp1-hp2||^2 = (1-cos theta)/2 = haversine 'a' = sin^2(theta/2) directly.
__global__ void centroid_xyz_kernel(const float* __restrict__ centroids,
                                    float* __restrict__ ct) {
    int c = blockIdx.x * blockDim.x + threadIdx.x;
    if (c >= C_) return;
    float lat = centroids[2 * c] * DEG2RAD;
    float lon = centroids[2 * c + 1] * DEG2RAD;
    float cl = cosf(lat);
    ct[c]          = 0.5f * cl * cosf(lon);
    ct[C_ + c]     = 0.5f * cl * sinf(lon);
    ct[2 * C_ + c] = 0.5f * sinf(lat);
}

__device__ __forceinline__ float wave_red_add(float v) {
#pragma unroll
    for (int off = 32; off > 0; off >>= 1) v += __shfl_down(v, off, 64);
    return v;
}

__device__ __forceinline__ void accum_pair(float lv, float xv, float yv, float zv,
                                           float x1, float y1, float z1,
                                           float& W, float& T, float& S) {
    float dx = xv - x1, dy = yv - y1, dz = zv - z1;
    float a = fmaf(dx, dx, fmaf(dy, dy, dz * dz));      // = sin^2(theta/2)
    float s = fminf(__builtin_amdgcn_sqrtf(a), 1.0f);   // sin(theta/2) in [0,1]
    float p = fmaf(s, A7, A6);
    p = fmaf(s, p, A5);
    p = fmaf(s, p, A4);
    p = fmaf(s, p, A3);
    p = fmaf(s, p, A2);
    p = fmaf(s, p, A1);
    p = fmaf(s, p, A0);
    float r = __builtin_amdgcn_sqrtf(1.0f - s);
    float asv = fmaf(-r, p, PI_2F);                     // asin(s)
    float w = __expf(asv * KN);                         // exp(-dist/tau)
    W += w;
    T = fmaf(w, lv, T);
    S += __expf(lv);
}

// One block per row. Single pass, three running sums:
//   W = sum w_c, T = sum w_c*l_c, S = sum exp(l_c);  loss_b = log(S) - T/W
__global__ __launch_bounds__(256) void row_loss_kernel(
    const float* __restrict__ logits, const float* __restrict__ latlon,
    const float* __restrict__ ct, float* __restrict__ row_loss) {
    const int b = blockIdx.x;
    const float lat1 = latlon[2 * b] * DEG2RAD;
    const float lon1 = latlon[2 * b + 1] * DEG2RAD;
    const float cl = cosf(lat1);
    const float x1 = 0.5f * cl * cosf(lon1);
    const float y1 = 0.5f * cl * sinf(lon1);
    const float z1 = 0.5f * sinf(lat1);

    const float4* __restrict__ l4 = (const float4*)(logits + (size_t)b * C_);
    const float4* __restrict__ X4 = (const float4*)(ct);
    const float4* __restrict__ Y4 = (const float4*)(ct + C_);
    const float4* __restrict__ Z4 = (const float4*)(ct + 2 * C_);

    float W = 0.f, T = 0.f, S = 0.f;
#pragma unroll 4
    for (int i = threadIdx.x; i < C_ / 4; i += 256) {
        float4 l = l4[i];
        float4 X = X4[i];
        float4 Y = Y4[i];
        float4 Z = Z4[i];
        accum_pair(l.x, X.x, Y.x, Z.x, x1, y1, z1, W, T, S);
        accum_pair(l.y, X.y, Y.y, Z.y, x1, y1, z1, W, T, S);
        accum_pair(l.z, X.z, Y.z, Z.z, x1, y1, z1, W, T, S);
        accum_pair(l.w, X.w, Y.w, Z.w, x1, y1, z1, W, T, S);
    }
    W = wave_red_add(W);
    T = wave_red_add(T);
    S = wave_red_add(S);
    __shared__ float red[3][4];
    const int lane = threadIdx.x & 63, wv = threadIdx.x >> 6;
    if (lane == 0) { red[0][wv] = W; red[1][wv] = T; red[2][wv] = S; }
    __syncthreads();
    if (threadIdx.x == 0) {
        float Wt = red[0][0] + red[0][1] + red[0][2] + red[0][3];
        float Tt = red[1][0] + red[1][1] + red[1][2] + red[1][3];
        float St = red[2][0] + red[2][1] + red[2][2] + red[2][3];
        Wt = fmaxf(Wt, 1e-30f);
        row_loss[b] = logf(St) - Tt / Wt;
    }
}

__global__ __launch_bounds__(256) void final_reduce_kernel(
    const float* __restrict__ row_loss, float* __restrict__ out) {
    float s = 0.f;
    for (int i = threadIdx.x; i < B_; i += 256) s += row_loss[i];
    s = wave_red_add(s);
    __shared__ float red[4];
    const int lane = threadIdx.x & 63, wv = threadIdx.x >> 6;
    if (lane == 0) red[wv] = s;
    __syncthreads();
    if (threadIdx.x == 0)
        out[0] = (red[0] + red[1] + red[2] + red[3]) * (1.0f / B_);
}

extern "C" void kernel_launch(void* const* d_in, const int* in_sizes, int n_in,
                              void* d_out, int out_size, void* d_ws, size_t ws_size,
                              hipStream_t stream) {
    const float* pred_logits = (const float*)d_in[0];  // [B, C] f32
    const float* latlon      = (const float*)d_in[1];  // [B, 2] f32
    const float* centroids   = (const float*)d_in[2];  // [C, 2] f32
    // d_in[3] geocell_indices is unused by the reference.
    float* ct       = (float*)d_ws;      // 3*C floats: half unit-sphere coords
    float* row_loss = ct + 3 * C_;       // B floats
    float* out      = (float*)d_out;

    centroid_xyz_kernel<<<(C_ + 255) / 256, 256, 0, stream>>>(centroids, ct);
    row_loss_kernel<<<B_, 256, 0, stream>>>(pred_logits, latlon, ct, row_loss);
    final_reduce_kernel<<<1, 256, 0, stream>>>(row_loss, out);
}